// Round 9
// baseline (1252.244 us; speedup 1.0000x reference)
//
#include <hip/hip_runtime.h>
#include <hip/hip_bf16.h>

#define HID 128

// ---------------------------------------------------------------------------
// degree count: deg[dst]++ over edges
__global__ void count_deg_kernel(const int* __restrict__ dst, int* __restrict__ deg, int ne) {
    int e = blockIdx.x * blockDim.x + threadIdx.x;
    if (e < ne) atomicAdd(&deg[dst[e]], 1);
}

// block-local exclusive scan of deg -> row_start (pre-offset), block totals -> partials
__global__ void scan_blocks_kernel(const int* __restrict__ deg, int* __restrict__ row_start,
                                   int* __restrict__ partials, int n) {
    __shared__ int sd[256];
    int t = threadIdx.x;
    int i = blockIdx.x * 256 + t;
    int v = (i < n) ? deg[i] : 0;
    sd[t] = v;
    __syncthreads();
    #pragma unroll
    for (int ofs = 1; ofs < 256; ofs <<= 1) {
        int x = (t >= ofs) ? sd[t - ofs] : 0;
        __syncthreads();
        sd[t] += x;
        __syncthreads();
    }
    if (i < n) row_start[i] = sd[t] - v;           // exclusive within block
    if (t == 255) partials[blockIdx.x] = sd[255];  // block total
}

// single-block exclusive scan of partials (nb <= 512)
__global__ void scan_partials_kernel(int* __restrict__ partials, int nb) {
    __shared__ int sd[512];
    int t = threadIdx.x;
    int v = (t < nb) ? partials[t] : 0;
    sd[t] = v;
    __syncthreads();
    #pragma unroll
    for (int ofs = 1; ofs < 512; ofs <<= 1) {
        int x = (t >= ofs) ? sd[t - ofs] : 0;
        __syncthreads();
        sd[t] += x;
        __syncthreads();
    }
    if (t < nb) partials[t] = sd[t] - v;           // exclusive across blocks
}

__global__ void scan_add_kernel(int* __restrict__ row_start, const int* __restrict__ partials, int n) {
    int i = blockIdx.x * 256 + threadIdx.x;
    if (i < n) row_start[i] += partials[blockIdx.x];
}

__global__ void dinv_kernel(const int* __restrict__ deg, float* __restrict__ dinv, int n) {
    int i = blockIdx.x * blockDim.x + threadIdx.x;
    if (i < n) dinv[i] = rsqrtf((float)deg[i] + 1.0f);
}

__global__ void fill_csr_kernel(const int* __restrict__ src, const int* __restrict__ dst,
                                const int* __restrict__ row_start, int* __restrict__ cursor,
                                int* __restrict__ csr_src, int ne) {
    int e = blockIdx.x * blockDim.x + threadIdx.x;
    if (e < ne) {
        int d = dst[e];
        int pos = atomicAdd(&cursor[d], 1);
        csr_src[row_start[d] + pos] = src[e];
    }
}

// rates -> enc MLP -> r[128]; rb[f] = sum_k r[k] * conv2_W[(128+k)*128+f]
__global__ void rvec_kernel(const float* __restrict__ rates,
                            const float* __restrict__ eW1, const float* __restrict__ eb1,
                            const float* __restrict__ eW2, const float* __restrict__ eb2,
                            const float* __restrict__ conv2W, float* __restrict__ rb) {
    __shared__ float r1[8];
    __shared__ float rv[128];
    int f = threadIdx.x;  // 128 threads
    if (f < 8) {
        float a = eb1[f];
        #pragma unroll
        for (int k = 0; k < 16; ++k) a += rates[k] * eW1[k * 8 + f];
        r1[f] = fmaxf(a, 0.f);
    }
    __syncthreads();
    float a = eb2[f];
    #pragma unroll
    for (int j = 0; j < 8; ++j) a += r1[j] * eW2[j * 128 + f];
    rv[f] = a;
    __syncthreads();
    float b = 0.f;
    for (int k = 0; k < 128; ++k) b += rv[k] * conv2W[(128 + k) * 128 + f];
    rb[f] = b;
}

// ---------------------------------------------------------------------------
// C[nrows][128] = ((X[nrows][128] @ W[128][128]) + bias) * dinv[row]
// W staged in LDS (64 KiB). block = 256 threads -> 64 rows x 128 cols;
// thread tile 4 rows x 8 cols. ALL per-thread state in NAMED scalars/float4s
// (no arrays) -> guaranteed VGPR allocation, no scratch (round-6 spill fix).
#define FMA8(xs, wa, wb, A, B)                                          \
    A.x += (xs) * wa.x; A.y += (xs) * wa.y;                             \
    A.z += (xs) * wa.z; A.w += (xs) * wa.w;                             \
    B.x += (xs) * wb.x; B.y += (xs) * wb.y;                             \
    B.z += (xs) * wb.z; B.w += (xs) * wb.w;

#define KSTEP(KK, COMP)                                                 \
    {                                                                   \
        const float* wr = &wl[(k0 + KK) * 128 + col0];                  \
        float4 wa = *reinterpret_cast<const float4*>(wr);               \
        float4 wb = *reinterpret_cast<const float4*>(wr + 4);           \
        FMA8(xv0.COMP, wa, wb, a0a, a0b)                                \
        FMA8(xv1.COMP, wa, wb, a1a, a1b)                                \
        FMA8(xv2.COMP, wa, wb, a2a, a2b)                                \
        FMA8(xv3.COMP, wa, wb, a3a, a3b)                                \
    }

#define STORE_ROW(R, A, B)                                              \
    {                                                                   \
        int row = r0 + R;                                               \
        if (row < nrows) {                                              \
            const float dv = dinv[row];                                 \
            float4 o1, o2;                                              \
            o1.x = (A.x + ba.x) * dv; o1.y = (A.y + ba.y) * dv;         \
            o1.z = (A.z + ba.z) * dv; o1.w = (A.w + ba.w) * dv;         \
            o2.x = (B.x + bb.x) * dv; o2.y = (B.y + bb.y) * dv;         \
            o2.z = (B.z + bb.z) * dv; o2.w = (B.w + bb.w) * dv;         \
            float* op = out + (size_t)row * 128 + col0;                 \
            *reinterpret_cast<float4*>(op) = o1;                        \
            *reinterpret_cast<float4*>(op + 4) = o2;                    \
        }                                                               \
    }

__global__ __launch_bounds__(256) void gemm128_kernel(
    const float* __restrict__ X, const float* __restrict__ W,
    const float* __restrict__ bias, const float* __restrict__ dinv,
    float* __restrict__ out, int nrows) {
    __shared__ float wl[128 * 128];
    for (int i = threadIdx.x; i < 128 * 32; i += 256)
        reinterpret_cast<float4*>(wl)[i] = reinterpret_cast<const float4*>(W)[i];
    __syncthreads();

    const int t = threadIdx.x;
    const int cg = t & 15;          // 16 col groups x 8 cols
    const int rg = t >> 4;          // 16 row groups x 4 rows
    const int col0 = cg * 8;
    const int r0 = blockIdx.x * 64 + rg * 4;

    const float* x0 = X + (size_t)min(r0 + 0, nrows - 1) * 128;
    const float* x1 = X + (size_t)min(r0 + 1, nrows - 1) * 128;
    const float* x2 = X + (size_t)min(r0 + 2, nrows - 1) * 128;
    const float* x3 = X + (size_t)min(r0 + 3, nrows - 1) * 128;

    float4 a0a = {0,0,0,0}, a0b = {0,0,0,0};
    float4 a1a = {0,0,0,0}, a1b = {0,0,0,0};
    float4 a2a = {0,0,0,0}, a2b = {0,0,0,0};
    float4 a3a = {0,0,0,0}, a3b = {0,0,0,0};

    for (int k0 = 0; k0 < 128; k0 += 4) {
        float4 xv0 = *reinterpret_cast<const float4*>(x0 + k0);
        float4 xv1 = *reinterpret_cast<const float4*>(x1 + k0);
        float4 xv2 = *reinterpret_cast<const float4*>(x2 + k0);
        float4 xv3 = *reinterpret_cast<const float4*>(x3 + k0);
        KSTEP(0, x)
        KSTEP(1, y)
        KSTEP(2, z)
        KSTEP(3, w)
    }

    float4 ba = {0,0,0,0}, bb = {0,0,0,0};
    if (bias) {
        ba = *reinterpret_cast<const float4*>(bias + col0);
        bb = *reinterpret_cast<const float4*>(bias + col0 + 4);
    }
    STORE_ROW(0, a0a, a0b)
    STORE_ROW(1, a1a, a1b)
    STORE_ROW(2, a2a, a2b)
    STORE_ROW(3, a3a, a3b)
}

// ---------------------------------------------------------------------------
// node-parallel gather aggregation over PRE-SCALED features hs = hlin*dinv:
//   out[n] = (sum_{src in in(n)} hs[src] + hs[n]) * dinv[n] + bias  [+relu] [+meanpool]
// Round-7 reshape: 128 threads = 4 groups x 32 lanes; group g owns node q*4+g
// and gathers whole 512B rows as float4 (16B/lane), 4 edges in flight.
#define ACC4(A, H) A.x += H.x; A.y += H.y; A.z += H.z; A.w += H.w;

template <bool RELU, bool STORE, bool MEANPOOL>
__global__ __launch_bounds__(128) void agg_kernel(
    const float* __restrict__ hs, float* __restrict__ out,
    const float* __restrict__ dinv, const int* __restrict__ row_start,
    const int* __restrict__ csr_src, const float* __restrict__ bias,
    float* __restrict__ gsum, int n_nodes, int n_edges) {
    const int l = threadIdx.x & 31;   // lane in group
    const int g = threadIdx.x >> 5;   // group 0..3
    const int f0 = l * 4;             // feature base (float4)
    const float4 bf = *reinterpret_cast<const float4*>(bias + f0);
    float4 msum = {0, 0, 0, 0};
    const int nq = (n_nodes + 3) >> 2;
    for (int q = blockIdx.x; q < nq; q += gridDim.x) {
        const int n = q * 4 + g;
        if (n < n_nodes) {
            const int s = row_start[n];
            const int e = (n + 1 < n_nodes) ? row_start[n + 1] : n_edges;
            float4 acc0 = {0,0,0,0}, acc1 = {0,0,0,0};
            float4 acc2 = {0,0,0,0}, acc3 = {0,0,0,0};
            int i = s;
            for (; i + 4 <= e; i += 4) {
                int s0 = csr_src[i + 0], s1 = csr_src[i + 1];
                int s2 = csr_src[i + 2], s3 = csr_src[i + 3];
                float4 h0 = *reinterpret_cast<const float4*>(hs + (size_t)s0 * 128 + f0);
                float4 h1 = *reinterpret_cast<const float4*>(hs + (size_t)s1 * 128 + f0);
                float4 h2 = *reinterpret_cast<const float4*>(hs + (size_t)s2 * 128 + f0);
                float4 h3 = *reinterpret_cast<const float4*>(hs + (size_t)s3 * 128 + f0);
                ACC4(acc0, h0) ACC4(acc1, h1) ACC4(acc2, h2) ACC4(acc3, h3)
            }
            for (; i < e; ++i) {
                int sI = csr_src[i];
                float4 hI = *reinterpret_cast<const float4*>(hs + (size_t)sI * 128 + f0);
                ACC4(acc0, hI)
            }
            const float di = dinv[n];
            const float4 self = *reinterpret_cast<const float4*>(hs + (size_t)n * 128 + f0);
            float4 v;
            v.x = (acc0.x + acc1.x + acc2.x + acc3.x + self.x) * di + bf.x;
            v.y = (acc0.y + acc1.y + acc2.y + acc3.y + self.y) * di + bf.y;
            v.z = (acc0.z + acc1.z + acc2.z + acc3.z + self.z) * di + bf.z;
            v.w = (acc0.w + acc1.w + acc2.w + acc3.w + self.w) * di + bf.w;
            if (RELU) {
                v.x = fmaxf(v.x, 0.f); v.y = fmaxf(v.y, 0.f);
                v.z = fmaxf(v.z, 0.f); v.w = fmaxf(v.w, 0.f);
            }
            if (STORE) *reinterpret_cast<float4*>(out + (size_t)n * 128 + f0) = v;
            if (MEANPOOL) { ACC4(msum, v) }
        }
    }
    if (MEANPOOL) {
        __shared__ float4 sred[4][32];
        sred[g][l] = msum;
        __syncthreads();
        if (g == 0) {
            float4 a = sred[0][l], b = sred[1][l], c = sred[2][l], d = sred[3][l];
            atomicAdd(&gsum[f0 + 0], a.x + b.x + c.x + d.x);
            atomicAdd(&gsum[f0 + 1], a.y + b.y + c.y + d.y);
            atomicAdd(&gsum[f0 + 2], a.z + b.z + c.z + d.z);
            atomicAdd(&gsum[f0 + 3], a.w + b.w + c.w + d.w);
        }
    }
}

// ---------------------------------------------------------------------------
// final small MLP on the pooled vector, single block
__global__ void mlp_kernel(const float* __restrict__ gsum,
                           const float* __restrict__ hidW, const float* __restrict__ hidb,
                           const float* __restrict__ hid2W, const float* __restrict__ hid2b,
                           const float* __restrict__ finW, const float* __restrict__ finb,
                           float* __restrict__ out, float inv_n) {
    __shared__ float g[128], t1[256], t2[128];
    int t = threadIdx.x;  // 256 threads
    if (t < 128) g[t] = gsum[t] * inv_n;
    __syncthreads();
    {
        float a = hidb[t];
        for (int k = 0; k < 128; ++k) a += g[k] * hidW[k * 256 + t];
        t1[t] = fmaxf(a, 0.f);
    }
    __syncthreads();
    if (t < 128) {
        float a = hid2b[t];
        for (int k = 0; k < 256; ++k) a += t1[k] * hid2W[k * 128 + t];
        t2[t] = fmaxf(a, 0.f);
    }
    __syncthreads();
    if (t < 2) {
        float a = finb[t];
        for (int k = 0; k < 128; ++k) a += t2[k] * finW[k * 2 + t];
        out[t] = a;
    }
}

// ---------------------------------------------------------------------------
extern "C" void kernel_launch(void* const* d_in, const int* in_sizes, int n_in,
                              void* d_out, int out_size, void* d_ws, size_t ws_size,
                              hipStream_t stream) {
    const float* graph  = (const float*)d_in[0];
    const int*   edge   = (const int*)d_in[1];
    const float* rates  = (const float*)d_in[2];
    const float* conv1W = (const float*)d_in[3];
    const float* conv1b = (const float*)d_in[4];
    const float* eW1    = (const float*)d_in[5];
    const float* eb1    = (const float*)d_in[6];
    const float* eW2    = (const float*)d_in[7];
    const float* eb2    = (const float*)d_in[8];
    const float* conv2W = (const float*)d_in[9];
    const float* conv2b = (const float*)d_in[10];
    const float* conv3W = (const float*)d_in[11];
    const float* conv3b = (const float*)d_in[12];
    const float* hidW   = (const float*)d_in[13];
    const float* hidb   = (const float*)d_in[14];
    const float* hid2W  = (const float*)d_in[15];
    const float* hid2b  = (const float*)d_in[16];
    const float* finW   = (const float*)d_in[17];
    const float* finb   = (const float*)d_in[18];

    const int NN = in_sizes[0] / 128;   // 100000
    const int NE = in_sizes[1] / 2;     // 1600000
    const int* src = edge;
    const int* dst = edge + NE;

    // workspace layout (512B aligned slots)
    char* ws = (char*)d_ws;
    size_t p = 0;
    auto alloc = [&](size_t bytes) { size_t o = p; p += (bytes + 511) & ~(size_t)511; return o; };
    int*   deg       = (int*)(ws + alloc((size_t)NN * 4));
    int*   cursor    = (int*)(ws + alloc((size_t)NN * 4));
    float* gsum      = (float*)(ws + alloc(512));
    const size_t zero_bytes = p;   // zero [0, p): deg, cursor, gsum
    float* dinv      = (float*)(ws + alloc((size_t)NN * 4));
    int*   row_start = (int*)(ws + alloc((size_t)NN * 4));
    int*   partials  = (int*)(ws + alloc(512 * 4));
    int*   csr       = (int*)(ws + alloc((size_t)NE * 4));
    float* rb        = (float*)(ws + alloc(512));
    float* bufA      = (float*)(ws + alloc((size_t)NN * 128 * 4));
    float* bufB      = (float*)(ws + alloc((size_t)NN * 128 * 4));
    if (p > ws_size) return;  // workspace too small: fail loudly (validation mismatch)

    const int SB = (NN + 255) / 256;    // scan blocks (391 <= 512)
    const int EB = (NE + 255) / 256;

    hipMemsetAsync(d_ws, 0, zero_bytes, stream);
    count_deg_kernel<<<EB, 256, 0, stream>>>(dst, deg, NE);
    scan_blocks_kernel<<<SB, 256, 0, stream>>>(deg, row_start, partials, NN);
    scan_partials_kernel<<<1, 512, 0, stream>>>(partials, SB);
    scan_add_kernel<<<SB, 256, 0, stream>>>(row_start, partials, NN);
    dinv_kernel<<<(NN + 255) / 256, 256, 0, stream>>>(deg, dinv, NN);
    fill_csr_kernel<<<EB, 256, 0, stream>>>(src, dst, row_start, cursor, csr, NE);
    rvec_kernel<<<1, 128, 0, stream>>>(rates, eW1, eb1, eW2, eb2, conv2W, rb);

    const int GB = (NN + 63) / 64;      // gemm blocks (1563)

    // conv1: h = relu(agg_scaled(graph@W1 * dinv) + b1)
    gemm128_kernel<<<GB, 256, 0, stream>>>(graph, conv1W, nullptr, dinv, bufA, NN);
    agg_kernel<true, true, false><<<4096, 128, 0, stream>>>(bufA, bufB, dinv, row_start, csr, conv1b, nullptr, NN, NE);
    // conv2: x = [h, r]; x@W2 = h@W2_top + rb  (rb folded pre-scale)
    gemm128_kernel<<<GB, 256, 0, stream>>>(bufB, conv2W, rb, dinv, bufA, NN);
    agg_kernel<false, true, false><<<4096, 128, 0, stream>>>(bufA, bufB, dinv, row_start, csr, conv2b, nullptr, NN, NE);
    // conv3 (+ fused mean pool)
    gemm128_kernel<<<GB, 256, 0, stream>>>(bufB, conv3W, nullptr, dinv, bufA, NN);
    agg_kernel<false, false, true><<<4096, 128, 0, stream>>>(bufA, nullptr, dinv, row_start, csr, conv3b, gsum, NN, NE);
    // pooled MLP head
    mlp_kernel<<<1, 256, 0, stream>>>(gsum, hidW, hidb, hid2W, hid2b, finW, finb, (float*)d_out, 1.0f / (float)NN);
}

// Round 10
// 986.178 us; speedup vs baseline: 1.2698x; 1.2698x over previous
//
#include <hip/hip_runtime.h>
#include <hip/hip_bf16.h>

#define HID 128

// ---------------------------------------------------------------------------
// degree count: deg[dst]++ over edges
__global__ void count_deg_kernel(const int* __restrict__ dst, int* __restrict__ deg, int ne) {
    int e = blockIdx.x * blockDim.x + threadIdx.x;
    if (e < ne) atomicAdd(&deg[dst[e]], 1);
}

// block-local exclusive scan of deg -> row_start (pre-offset), block totals -> partials
__global__ void scan_blocks_kernel(const int* __restrict__ deg, int* __restrict__ row_start,
                                   int* __restrict__ partials, int n) {
    __shared__ int sd[256];
    int t = threadIdx.x;
    int i = blockIdx.x * 256 + t;
    int v = (i < n) ? deg[i] : 0;
    sd[t] = v;
    __syncthreads();
    #pragma unroll
    for (int ofs = 1; ofs < 256; ofs <<= 1) {
        int x = (t >= ofs) ? sd[t - ofs] : 0;
        __syncthreads();
        sd[t] += x;
        __syncthreads();
    }
    if (i < n) row_start[i] = sd[t] - v;           // exclusive within block
    if (t == 255) partials[blockIdx.x] = sd[255];  // block total
}

// single-block exclusive scan of partials (nb <= 512)
__global__ void scan_partials_kernel(int* __restrict__ partials, int nb) {
    __shared__ int sd[512];
    int t = threadIdx.x;
    int v = (t < nb) ? partials[t] : 0;
    sd[t] = v;
    __syncthreads();
    #pragma unroll
    for (int ofs = 1; ofs < 512; ofs <<= 1) {
        int x = (t >= ofs) ? sd[t - ofs] : 0;
        __syncthreads();
        sd[t] += x;
        __syncthreads();
    }
    if (t < nb) partials[t] = sd[t] - v;           // exclusive across blocks
}

__global__ void scan_add_kernel(int* __restrict__ row_start, const int* __restrict__ partials, int n) {
    int i = blockIdx.x * 256 + threadIdx.x;
    if (i < n) row_start[i] += partials[blockIdx.x];
}

__global__ void dinv_kernel(const int* __restrict__ deg, float* __restrict__ dinv, int n) {
    int i = blockIdx.x * blockDim.x + threadIdx.x;
    if (i < n) dinv[i] = rsqrtf((float)deg[i] + 1.0f);
}

__global__ void fill_csr_kernel(const int* __restrict__ src, const int* __restrict__ dst,
                                const int* __restrict__ row_start, int* __restrict__ cursor,
                                int* __restrict__ csr_src, int ne) {
    int e = blockIdx.x * blockDim.x + threadIdx.x;
    if (e < ne) {
        int d = dst[e];
        int pos = atomicAdd(&cursor[d], 1);
        csr_src[row_start[d] + pos] = src[e];
    }
}

// rates -> enc MLP -> r[128]; rb[f] = sum_k r[k] * conv2_W[(128+k)*128+f]
__global__ void rvec_kernel(const float* __restrict__ rates,
                            const float* __restrict__ eW1, const float* __restrict__ eb1,
                            const float* __restrict__ eW2, const float* __restrict__ eb2,
                            const float* __restrict__ conv2W, float* __restrict__ rb) {
    __shared__ float r1[8];
    __shared__ float rv[128];
    int f = threadIdx.x;  // 128 threads
    if (f < 8) {
        float a = eb1[f];
        #pragma unroll
        for (int k = 0; k < 16; ++k) a += rates[k] * eW1[k * 8 + f];
        r1[f] = fmaxf(a, 0.f);
    }
    __syncthreads();
    float a = eb2[f];
    #pragma unroll
    for (int j = 0; j < 8; ++j) a += r1[j] * eW2[j * 128 + f];
    rv[f] = a;
    __syncthreads();
    float b = 0.f;
    for (int k = 0; k < 128; ++k) b += rv[k] * conv2W[(128 + k) * 128 + f];
    rb[f] = b;
}

// ---------------------------------------------------------------------------
// C[nrows][128] = ((X[nrows][128] @ W[128][128]) + bias) * dinv[row]
// W staged in LDS (64 KiB). block = 256 threads -> 64 rows x 128 cols;
// thread tile 4 rows x 8 cols. ALL per-thread state in NAMED scalars/float4s
// (no arrays) -> guaranteed VGPR allocation, no scratch (round-6 spill fix).
#define FMA8(xs, wa, wb, A, B)                                          \
    A.x += (xs) * wa.x; A.y += (xs) * wa.y;                             \
    A.z += (xs) * wa.z; A.w += (xs) * wa.w;                             \
    B.x += (xs) * wb.x; B.y += (xs) * wb.y;                             \
    B.z += (xs) * wb.z; B.w += (xs) * wb.w;

#define KSTEP(KK, COMP)                                                 \
    {                                                                   \
        const float* wr = &wl[(k0 + KK) * 128 + col0];                  \
        float4 wa = *reinterpret_cast<const float4*>(wr);               \
        float4 wb = *reinterpret_cast<const float4*>(wr + 4);           \
        FMA8(xv0.COMP, wa, wb, a0a, a0b)                                \
        FMA8(xv1.COMP, wa, wb, a1a, a1b)                                \
        FMA8(xv2.COMP, wa, wb, a2a, a2b)                                \
        FMA8(xv3.COMP, wa, wb, a3a, a3b)                                \
    }

#define STORE_ROW(R, A, B)                                              \
    {                                                                   \
        int row = r0 + R;                                               \
        if (row < nrows) {                                              \
            const float dv = dinv[row];                                 \
            float4 o1, o2;                                              \
            o1.x = (A.x + ba.x) * dv; o1.y = (A.y + ba.y) * dv;         \
            o1.z = (A.z + ba.z) * dv; o1.w = (A.w + ba.w) * dv;         \
            o2.x = (B.x + bb.x) * dv; o2.y = (B.y + bb.y) * dv;         \
            o2.z = (B.z + bb.z) * dv; o2.w = (B.w + bb.w) * dv;         \
            float* op = out + (size_t)row * 128 + col0;                 \
            *reinterpret_cast<float4*>(op) = o1;                        \
            *reinterpret_cast<float4*>(op + 4) = o2;                    \
        }                                                               \
    }

__global__ __launch_bounds__(256) void gemm128_kernel(
    const float* __restrict__ X, const float* __restrict__ W,
    const float* __restrict__ bias, const float* __restrict__ dinv,
    float* __restrict__ out, int nrows) {
    __shared__ float wl[128 * 128];
    for (int i = threadIdx.x; i < 128 * 32; i += 256)
        reinterpret_cast<float4*>(wl)[i] = reinterpret_cast<const float4*>(W)[i];
    __syncthreads();

    const int t = threadIdx.x;
    const int cg = t & 15;          // 16 col groups x 8 cols
    const int rg = t >> 4;          // 16 row groups x 4 rows
    const int col0 = cg * 8;
    const int r0 = blockIdx.x * 64 + rg * 4;

    const float* x0 = X + (size_t)min(r0 + 0, nrows - 1) * 128;
    const float* x1 = X + (size_t)min(r0 + 1, nrows - 1) * 128;
    const float* x2 = X + (size_t)min(r0 + 2, nrows - 1) * 128;
    const float* x3 = X + (size_t)min(r0 + 3, nrows - 1) * 128;

    float4 a0a = {0,0,0,0}, a0b = {0,0,0,0};
    float4 a1a = {0,0,0,0}, a1b = {0,0,0,0};
    float4 a2a = {0,0,0,0}, a2b = {0,0,0,0};
    float4 a3a = {0,0,0,0}, a3b = {0,0,0,0};

    for (int k0 = 0; k0 < 128; k0 += 4) {
        float4 xv0 = *reinterpret_cast<const float4*>(x0 + k0);
        float4 xv1 = *reinterpret_cast<const float4*>(x1 + k0);
        float4 xv2 = *reinterpret_cast<const float4*>(x2 + k0);
        float4 xv3 = *reinterpret_cast<const float4*>(x3 + k0);
        KSTEP(0, x)
        KSTEP(1, y)
        KSTEP(2, z)
        KSTEP(3, w)
    }

    float4 ba = {0,0,0,0}, bb = {0,0,0,0};
    if (bias) {
        ba = *reinterpret_cast<const float4*>(bias + col0);
        bb = *reinterpret_cast<const float4*>(bias + col0 + 4);
    }
    STORE_ROW(0, a0a, a0b)
    STORE_ROW(1, a1a, a1b)
    STORE_ROW(2, a2a, a2b)
    STORE_ROW(3, a3a, a3b)
}

// ---------------------------------------------------------------------------
// node-parallel gather aggregation over PRE-SCALED features hs = hlin*dinv:
//   out[n] = (sum_{src in in(n)} hs[src] + hs[n]) * dinv[n] + bias  [+relu] [+meanpool]
// Round-9: ONE FULL WAVE (64 lanes) per node -> zero intra-wave divergence
// (round-7's 32-lane groups split a wave across nodes with different degrees).
// Lane owns features (2l, 2l+1) as float2: 512B/edge per wave, 8 edges in
// flight = 64B/lane outstanding, half of round-6's instruction count.
#define ACC2(A, H) A.x += H.x; A.y += H.y;

template <bool RELU, bool STORE, bool MEANPOOL>
__global__ __launch_bounds__(256) void agg_kernel(
    const float* __restrict__ hs, float* __restrict__ out,
    const float* __restrict__ dinv, const int* __restrict__ row_start,
    const int* __restrict__ csr_src, const float* __restrict__ bias,
    float* __restrict__ gsum, int n_nodes, int n_edges) {
    const int l = threadIdx.x & 63;   // lane in wave
    const int w = threadIdx.x >> 6;   // wave 0..3
    const int f0 = l * 2;             // feature base (float2)
    const float2 bf = *reinterpret_cast<const float2*>(bias + f0);
    float2 msum = {0, 0};
    const int stride = gridDim.x * 4;
    for (int n = blockIdx.x * 4 + w; n < n_nodes; n += stride) {
        const int s = row_start[n];
        const int e = (n + 1 < n_nodes) ? row_start[n + 1] : n_edges;
        float2 a0 = {0,0}, a1 = {0,0}, a2 = {0,0}, a3 = {0,0};
        float2 a4 = {0,0}, a5 = {0,0}, a6 = {0,0}, a7 = {0,0};
        int i = s;
        for (; i + 8 <= e; i += 8) {
            int s0 = csr_src[i + 0], s1 = csr_src[i + 1];
            int s2 = csr_src[i + 2], s3 = csr_src[i + 3];
            int s4 = csr_src[i + 4], s5 = csr_src[i + 5];
            int s6 = csr_src[i + 6], s7 = csr_src[i + 7];
            float2 h0 = *reinterpret_cast<const float2*>(hs + (size_t)s0 * 128 + f0);
            float2 h1 = *reinterpret_cast<const float2*>(hs + (size_t)s1 * 128 + f0);
            float2 h2 = *reinterpret_cast<const float2*>(hs + (size_t)s2 * 128 + f0);
            float2 h3 = *reinterpret_cast<const float2*>(hs + (size_t)s3 * 128 + f0);
            float2 h4 = *reinterpret_cast<const float2*>(hs + (size_t)s4 * 128 + f0);
            float2 h5 = *reinterpret_cast<const float2*>(hs + (size_t)s5 * 128 + f0);
            float2 h6 = *reinterpret_cast<const float2*>(hs + (size_t)s6 * 128 + f0);
            float2 h7 = *reinterpret_cast<const float2*>(hs + (size_t)s7 * 128 + f0);
            ACC2(a0, h0) ACC2(a1, h1) ACC2(a2, h2) ACC2(a3, h3)
            ACC2(a4, h4) ACC2(a5, h5) ACC2(a6, h6) ACC2(a7, h7)
        }
        for (; i < e; ++i) {
            int sI = csr_src[i];
            float2 hI = *reinterpret_cast<const float2*>(hs + (size_t)sI * 128 + f0);
            ACC2(a0, hI)
        }
        const float di = dinv[n];
        const float2 self = *reinterpret_cast<const float2*>(hs + (size_t)n * 128 + f0);
        float2 v;
        v.x = (((a0.x + a1.x) + (a2.x + a3.x)) + ((a4.x + a5.x) + (a6.x + a7.x)) + self.x) * di + bf.x;
        v.y = (((a0.y + a1.y) + (a2.y + a3.y)) + ((a4.y + a5.y) + (a6.y + a7.y)) + self.y) * di + bf.y;
        if (RELU) { v.x = fmaxf(v.x, 0.f); v.y = fmaxf(v.y, 0.f); }
        if (STORE) *reinterpret_cast<float2*>(out + (size_t)n * 128 + f0) = v;
        if (MEANPOOL) { ACC2(msum, v) }
    }
    if (MEANPOOL) {
        __shared__ float2 sred[4][64];
        sred[w][l] = msum;
        __syncthreads();
        if (w == 0) {
            float2 a = sred[0][l], b = sred[1][l], c = sred[2][l], d = sred[3][l];
            atomicAdd(&gsum[f0 + 0], (a.x + b.x) + (c.x + d.x));
            atomicAdd(&gsum[f0 + 1], (a.y + b.y) + (c.y + d.y));
        }
    }
}

// ---------------------------------------------------------------------------
// final small MLP on the pooled vector, single block
__global__ void mlp_kernel(const float* __restrict__ gsum,
                           const float* __restrict__ hidW, const float* __restrict__ hidb,
                           const float* __restrict__ hid2W, const float* __restrict__ hid2b,
                           const float* __restrict__ finW, const float* __restrict__ finb,
                           float* __restrict__ out, float inv_n) {
    __shared__ float g[128], t1[256], t2[128];
    int t = threadIdx.x;  // 256 threads
    if (t < 128) g[t] = gsum[t] * inv_n;
    __syncthreads();
    {
        float a = hidb[t];
        for (int k = 0; k < 128; ++k) a += g[k] * hidW[k * 256 + t];
        t1[t] = fmaxf(a, 0.f);
    }
    __syncthreads();
    if (t < 128) {
        float a = hid2b[t];
        for (int k = 0; k < 256; ++k) a += t1[k] * hid2W[k * 128 + t];
        t2[t] = fmaxf(a, 0.f);
    }
    __syncthreads();
    if (t < 2) {
        float a = finb[t];
        for (int k = 0; k < 128; ++k) a += t2[k] * finW[k * 2 + t];
        out[t] = a;
    }
}

// ---------------------------------------------------------------------------
extern "C" void kernel_launch(void* const* d_in, const int* in_sizes, int n_in,
                              void* d_out, int out_size, void* d_ws, size_t ws_size,
                              hipStream_t stream) {
    const float* graph  = (const float*)d_in[0];
    const int*   edge   = (const int*)d_in[1];
    const float* rates  = (const float*)d_in[2];
    const float* conv1W = (const float*)d_in[3];
    const float* conv1b = (const float*)d_in[4];
    const float* eW1    = (const float*)d_in[5];
    const float* eb1    = (const float*)d_in[6];
    const float* eW2    = (const float*)d_in[7];
    const float* eb2    = (const float*)d_in[8];
    const float* conv2W = (const float*)d_in[9];
    const float* conv2b = (const float*)d_in[10];
    const float* conv3W = (const float*)d_in[11];
    const float* conv3b = (const float*)d_in[12];
    const float* hidW   = (const float*)d_in[13];
    const float* hidb   = (const float*)d_in[14];
    const float* hid2W  = (const float*)d_in[15];
    const float* hid2b  = (const float*)d_in[16];
    const float* finW   = (const float*)d_in[17];
    const float* finb   = (const float*)d_in[18];

    const int NN = in_sizes[0] / 128;   // 100000
    const int NE = in_sizes[1] / 2;     // 1600000
    const int* src = edge;
    const int* dst = edge + NE;

    // workspace layout (512B aligned slots)
    char* ws = (char*)d_ws;
    size_t p = 0;
    auto alloc = [&](size_t bytes) { size_t o = p; p += (bytes + 511) & ~(size_t)511; return o; };
    int*   deg       = (int*)(ws + alloc((size_t)NN * 4));
    int*   cursor    = (int*)(ws + alloc((size_t)NN * 4));
    float* gsum      = (float*)(ws + alloc(512));
    const size_t zero_bytes = p;   // zero [0, p): deg, cursor, gsum
    float* dinv      = (float*)(ws + alloc((size_t)NN * 4));
    int*   row_start = (int*)(ws + alloc((size_t)NN * 4));
    int*   partials  = (int*)(ws + alloc(512 * 4));
    int*   csr       = (int*)(ws + alloc((size_t)NE * 4));
    float* rb        = (float*)(ws + alloc(512));
    float* bufA      = (float*)(ws + alloc((size_t)NN * 128 * 4));
    float* bufB      = (float*)(ws + alloc((size_t)NN * 128 * 4));
    if (p > ws_size) return;  // workspace too small: fail loudly (validation mismatch)

    const int SB = (NN + 255) / 256;    // scan blocks (391 <= 512)
    const int EB = (NE + 255) / 256;

    hipMemsetAsync(d_ws, 0, zero_bytes, stream);
    count_deg_kernel<<<EB, 256, 0, stream>>>(dst, deg, NE);
    scan_blocks_kernel<<<SB, 256, 0, stream>>>(deg, row_start, partials, NN);
    scan_partials_kernel<<<1, 512, 0, stream>>>(partials, SB);
    scan_add_kernel<<<SB, 256, 0, stream>>>(row_start, partials, NN);
    dinv_kernel<<<(NN + 255) / 256, 256, 0, stream>>>(deg, dinv, NN);
    fill_csr_kernel<<<EB, 256, 0, stream>>>(src, dst, row_start, cursor, csr, NE);
    rvec_kernel<<<1, 128, 0, stream>>>(rates, eW1, eb1, eW2, eb2, conv2W, rb);

    const int GB = (NN + 63) / 64;      // gemm blocks (1563)
    const int AB = 2048;                // agg blocks: 4 waves/block, 8/CU resident

    // conv1: h = relu(agg_scaled(graph@W1 * dinv) + b1)
    gemm128_kernel<<<GB, 256, 0, stream>>>(graph, conv1W, nullptr, dinv, bufA, NN);
    agg_kernel<true, true, false><<<AB, 256, 0, stream>>>(bufA, bufB, dinv, row_start, csr, conv1b, nullptr, NN, NE);
    // conv2: x = [h, r]; x@W2 = h@W2_top + rb  (rb folded pre-scale)
    gemm128_kernel<<<GB, 256, 0, stream>>>(bufB, conv2W, rb, dinv, bufA, NN);
    agg_kernel<false, true, false><<<AB, 256, 0, stream>>>(bufA, bufB, dinv, row_start, csr, conv2b, nullptr, NN, NE);
    // conv3 (+ fused mean pool)
    gemm128_kernel<<<GB, 256, 0, stream>>>(bufB, conv3W, nullptr, dinv, bufA, NN);
    agg_kernel<false, false, true><<<AB, 256, 0, stream>>>(bufA, nullptr, dinv, row_start, csr, conv3b, gsum, NN, NE);
    // pooled MLP head
    mlp_kernel<<<1, 256, 0, stream>>>(gsum, hidW, hidb, hid2W, hid2b, finW, finb, (float*)d_out, 1.0f / (float)NN);
}

// Round 11
// 823.762 us; speedup vs baseline: 1.5202x; 1.1972x over previous
//
#include <hip/hip_runtime.h>
#include <hip/hip_bf16.h>

#define HID 128

__device__ inline unsigned pack_bf2(float lo, float hi) {
    union { __hip_bfloat162 v; unsigned u; } c;
    c.v.x = __float2bfloat16(lo);
    c.v.y = __float2bfloat16(hi);
    return c.u;
}

// ---------------------------------------------------------------------------
// degree count: deg[dst]++ over edges
__global__ void count_deg_kernel(const int* __restrict__ dst, int* __restrict__ deg, int ne) {
    int e = blockIdx.x * blockDim.x + threadIdx.x;
    if (e < ne) atomicAdd(&deg[dst[e]], 1);
}

// block-local exclusive scan of deg -> row_start (pre-offset), block totals -> partials
__global__ void scan_blocks_kernel(const int* __restrict__ deg, int* __restrict__ row_start,
                                   int* __restrict__ partials, int n) {
    __shared__ int sd[256];
    int t = threadIdx.x;
    int i = blockIdx.x * 256 + t;
    int v = (i < n) ? deg[i] : 0;
    sd[t] = v;
    __syncthreads();
    #pragma unroll
    for (int ofs = 1; ofs < 256; ofs <<= 1) {
        int x = (t >= ofs) ? sd[t - ofs] : 0;
        __syncthreads();
        sd[t] += x;
        __syncthreads();
    }
    if (i < n) row_start[i] = sd[t] - v;           // exclusive within block
    if (t == 255) partials[blockIdx.x] = sd[255];  // block total
}

// single-block exclusive scan of partials (nb <= 512)
__global__ void scan_partials_kernel(int* __restrict__ partials, int nb) {
    __shared__ int sd[512];
    int t = threadIdx.x;
    int v = (t < nb) ? partials[t] : 0;
    sd[t] = v;
    __syncthreads();
    #pragma unroll
    for (int ofs = 1; ofs < 512; ofs <<= 1) {
        int x = (t >= ofs) ? sd[t - ofs] : 0;
        __syncthreads();
        sd[t] += x;
        __syncthreads();
    }
    if (t < nb) partials[t] = sd[t] - v;           // exclusive across blocks
}

__global__ void scan_add_kernel(int* __restrict__ row_start, const int* __restrict__ partials, int n) {
    int i = blockIdx.x * 256 + threadIdx.x;
    if (i < n) row_start[i] += partials[blockIdx.x];
}

__global__ void dinv_kernel(const int* __restrict__ deg, float* __restrict__ dinv, int n) {
    int i = blockIdx.x * blockDim.x + threadIdx.x;
    if (i < n) dinv[i] = rsqrtf((float)deg[i] + 1.0f);
}

__global__ void fill_csr_kernel(const int* __restrict__ src, const int* __restrict__ dst,
                                const int* __restrict__ row_start, int* __restrict__ cursor,
                                int* __restrict__ csr_src, int ne) {
    int e = blockIdx.x * blockDim.x + threadIdx.x;
    if (e < ne) {
        int d = dst[e];
        int pos = atomicAdd(&cursor[d], 1);
        csr_src[row_start[d] + pos] = src[e];
    }
}

// rates -> enc MLP -> r[128]; rb[f] = sum_k r[k] * conv2_W[(128+k)*128+f]
__global__ void rvec_kernel(const float* __restrict__ rates,
                            const float* __restrict__ eW1, const float* __restrict__ eb1,
                            const float* __restrict__ eW2, const float* __restrict__ eb2,
                            const float* __restrict__ conv2W, float* __restrict__ rb) {
    __shared__ float r1[8];
    __shared__ float rv[128];
    int f = threadIdx.x;  // 128 threads
    if (f < 8) {
        float a = eb1[f];
        #pragma unroll
        for (int k = 0; k < 16; ++k) a += rates[k] * eW1[k * 8 + f];
        r1[f] = fmaxf(a, 0.f);
    }
    __syncthreads();
    float a = eb2[f];
    #pragma unroll
    for (int j = 0; j < 8; ++j) a += r1[j] * eW2[j * 128 + f];
    rv[f] = a;
    __syncthreads();
    float b = 0.f;
    for (int k = 0; k < 128; ++k) b += rv[k] * conv2W[(128 + k) * 128 + f];
    rb[f] = b;
}

// ---------------------------------------------------------------------------
// hs[nrows][128] (bf16) = ((X[nrows][128] @ W[128][128]) + bias) * dinv[row]
// W staged in LDS (64 KiB). block = 256 threads -> 64 rows x 128 cols;
// thread tile 4 rows x 8 cols, all state in named scalars (round-6 spill fix).
// Round-10 change: epilogue packs 8 fp32 -> 8 bf16 (one 16B uint4 store).
#define FMA8(xs, wa, wb, A, B)                                          \
    A.x += (xs) * wa.x; A.y += (xs) * wa.y;                             \
    A.z += (xs) * wa.z; A.w += (xs) * wa.w;                             \
    B.x += (xs) * wb.x; B.y += (xs) * wb.y;                             \
    B.z += (xs) * wb.z; B.w += (xs) * wb.w;

#define KSTEP(KK, COMP)                                                 \
    {                                                                   \
        const float* wr = &wl[(k0 + KK) * 128 + col0];                  \
        float4 wa = *reinterpret_cast<const float4*>(wr);               \
        float4 wb = *reinterpret_cast<const float4*>(wr + 4);           \
        FMA8(xv0.COMP, wa, wb, a0a, a0b)                                \
        FMA8(xv1.COMP, wa, wb, a1a, a1b)                                \
        FMA8(xv2.COMP, wa, wb, a2a, a2b)                                \
        FMA8(xv3.COMP, wa, wb, a3a, a3b)                                \
    }

#define STORE_ROW(R, A, B)                                              \
    {                                                                   \
        int row = r0 + R;                                               \
        if (row < nrows) {                                              \
            const float dv = dinv[row];                                 \
            uint4 o;                                                    \
            o.x = pack_bf2((A.x + ba.x) * dv, (A.y + ba.y) * dv);       \
            o.y = pack_bf2((A.z + ba.z) * dv, (A.w + ba.w) * dv);       \
            o.z = pack_bf2((B.x + bb.x) * dv, (B.y + bb.y) * dv);       \
            o.w = pack_bf2((B.z + bb.z) * dv, (B.w + bb.w) * dv);       \
            *reinterpret_cast<uint4*>(out + (size_t)row * 128 + col0) = o; \
        }                                                               \
    }

__global__ __launch_bounds__(256) void gemm128_kernel(
    const float* __restrict__ X, const float* __restrict__ W,
    const float* __restrict__ bias, const float* __restrict__ dinv,
    __hip_bfloat16* __restrict__ out, int nrows) {
    __shared__ float wl[128 * 128];
    for (int i = threadIdx.x; i < 128 * 32; i += 256)
        reinterpret_cast<float4*>(wl)[i] = reinterpret_cast<const float4*>(W)[i];
    __syncthreads();

    const int t = threadIdx.x;
    const int cg = t & 15;          // 16 col groups x 8 cols
    const int rg = t >> 4;          // 16 row groups x 4 rows
    const int col0 = cg * 8;
    const int r0 = blockIdx.x * 64 + rg * 4;

    const float* x0 = X + (size_t)min(r0 + 0, nrows - 1) * 128;
    const float* x1 = X + (size_t)min(r0 + 1, nrows - 1) * 128;
    const float* x2 = X + (size_t)min(r0 + 2, nrows - 1) * 128;
    const float* x3 = X + (size_t)min(r0 + 3, nrows - 1) * 128;

    float4 a0a = {0,0,0,0}, a0b = {0,0,0,0};
    float4 a1a = {0,0,0,0}, a1b = {0,0,0,0};
    float4 a2a = {0,0,0,0}, a2b = {0,0,0,0};
    float4 a3a = {0,0,0,0}, a3b = {0,0,0,0};

    for (int k0 = 0; k0 < 128; k0 += 4) {
        float4 xv0 = *reinterpret_cast<const float4*>(x0 + k0);
        float4 xv1 = *reinterpret_cast<const float4*>(x1 + k0);
        float4 xv2 = *reinterpret_cast<const float4*>(x2 + k0);
        float4 xv3 = *reinterpret_cast<const float4*>(x3 + k0);
        KSTEP(0, x)
        KSTEP(1, y)
        KSTEP(2, z)
        KSTEP(3, w)
    }

    float4 ba = {0,0,0,0}, bb = {0,0,0,0};
    if (bias) {
        ba = *reinterpret_cast<const float4*>(bias + col0);
        bb = *reinterpret_cast<const float4*>(bias + col0 + 4);
    }
    STORE_ROW(0, a0a, a0b)
    STORE_ROW(1, a1a, a1b)
    STORE_ROW(2, a2a, a2b)
    STORE_ROW(3, a3a, a3b)
}

// ---------------------------------------------------------------------------
// node-parallel gather aggregation over PRE-SCALED bf16 features hs = hlin*dinv:
//   out[n] = (sum_{src in in(n)} hs[src] + hs[n]) * dinv[n] + bias  [+relu] [+meanpool]
// Round-6 structure (proven best: block-per-node, thread=feature, 8-deep ILP);
// round-10 change: hs is bf16 -> 2B loads, half the fetched bytes.
template <bool RELU, bool STORE, bool MEANPOOL>
__global__ __launch_bounds__(128) void agg_kernel(
    const __hip_bfloat16* __restrict__ hs, float* __restrict__ out,
    const float* __restrict__ dinv, const int* __restrict__ row_start,
    const int* __restrict__ csr_src, const float* __restrict__ bias,
    float* __restrict__ gsum, int n_nodes, int n_edges) {
    const int f = threadIdx.x;
    const float bf = bias[f];
    float msum = 0.f;
    for (int n = blockIdx.x; n < n_nodes; n += gridDim.x) {
        const int s = row_start[n];
        const int e = (n + 1 < n_nodes) ? row_start[n + 1] : n_edges;
        float acc0 = 0.f, acc1 = 0.f;
        int i = s;
        for (; i + 8 <= e; i += 8) {
            int s0 = csr_src[i + 0], s1 = csr_src[i + 1];
            int s2 = csr_src[i + 2], s3 = csr_src[i + 3];
            int s4 = csr_src[i + 4], s5 = csr_src[i + 5];
            int s6 = csr_src[i + 6], s7 = csr_src[i + 7];
            float h0 = __bfloat162float(hs[(size_t)s0 * 128 + f]);
            float h1 = __bfloat162float(hs[(size_t)s1 * 128 + f]);
            float h2 = __bfloat162float(hs[(size_t)s2 * 128 + f]);
            float h3 = __bfloat162float(hs[(size_t)s3 * 128 + f]);
            float h4 = __bfloat162float(hs[(size_t)s4 * 128 + f]);
            float h5 = __bfloat162float(hs[(size_t)s5 * 128 + f]);
            float h6 = __bfloat162float(hs[(size_t)s6 * 128 + f]);
            float h7 = __bfloat162float(hs[(size_t)s7 * 128 + f]);
            acc0 += (h0 + h1) + (h2 + h3);
            acc1 += (h4 + h5) + (h6 + h7);
        }
        for (; i < e; ++i) {
            int sI = csr_src[i];
            acc0 += __bfloat162float(hs[(size_t)sI * 128 + f]);
        }
        const float di = dinv[n];
        const float self = __bfloat162float(hs[(size_t)n * 128 + f]);
        float v = (acc0 + acc1 + self) * di + bf;
        if (RELU) v = fmaxf(v, 0.f);
        if (STORE) out[(size_t)n * 128 + f] = v;
        if (MEANPOOL) msum += v;
    }
    if (MEANPOOL) atomicAdd(&gsum[f], msum);
}

// ---------------------------------------------------------------------------
// final small MLP on the pooled vector, single block
__global__ void mlp_kernel(const float* __restrict__ gsum,
                           const float* __restrict__ hidW, const float* __restrict__ hidb,
                           const float* __restrict__ hid2W, const float* __restrict__ hid2b,
                           const float* __restrict__ finW, const float* __restrict__ finb,
                           float* __restrict__ out, float inv_n) {
    __shared__ float g[128], t1[256], t2[128];
    int t = threadIdx.x;  // 256 threads
    if (t < 128) g[t] = gsum[t] * inv_n;
    __syncthreads();
    {
        float a = hidb[t];
        for (int k = 0; k < 128; ++k) a += g[k] * hidW[k * 256 + t];
        t1[t] = fmaxf(a, 0.f);
    }
    __syncthreads();
    if (t < 128) {
        float a = hid2b[t];
        for (int k = 0; k < 256; ++k) a += t1[k] * hid2W[k * 128 + t];
        t2[t] = fmaxf(a, 0.f);
    }
    __syncthreads();
    if (t < 2) {
        float a = finb[t];
        for (int k = 0; k < 128; ++k) a += t2[k] * finW[k * 2 + t];
        out[t] = a;
    }
}

// ---------------------------------------------------------------------------
extern "C" void kernel_launch(void* const* d_in, const int* in_sizes, int n_in,
                              void* d_out, int out_size, void* d_ws, size_t ws_size,
                              hipStream_t stream) {
    const float* graph  = (const float*)d_in[0];
    const int*   edge   = (const int*)d_in[1];
    const float* rates  = (const float*)d_in[2];
    const float* conv1W = (const float*)d_in[3];
    const float* conv1b = (const float*)d_in[4];
    const float* eW1    = (const float*)d_in[5];
    const float* eb1    = (const float*)d_in[6];
    const float* eW2    = (const float*)d_in[7];
    const float* eb2    = (const float*)d_in[8];
    const float* conv2W = (const float*)d_in[9];
    const float* conv2b = (const float*)d_in[10];
    const float* conv3W = (const float*)d_in[11];
    const float* conv3b = (const float*)d_in[12];
    const float* hidW   = (const float*)d_in[13];
    const float* hidb   = (const float*)d_in[14];
    const float* hid2W  = (const float*)d_in[15];
    const float* hid2b  = (const float*)d_in[16];
    const float* finW   = (const float*)d_in[17];
    const float* finb   = (const float*)d_in[18];

    const int NN = in_sizes[0] / 128;   // 100000
    const int NE = in_sizes[1] / 2;     // 1600000
    const int* src = edge;
    const int* dst = edge + NE;

    // workspace layout (512B aligned slots)
    char* ws = (char*)d_ws;
    size_t p = 0;
    auto alloc = [&](size_t bytes) { size_t o = p; p += (bytes + 511) & ~(size_t)511; return o; };
    int*   deg       = (int*)(ws + alloc((size_t)NN * 4));
    int*   cursor    = (int*)(ws + alloc((size_t)NN * 4));
    float* gsum      = (float*)(ws + alloc(512));
    const size_t zero_bytes = p;   // zero [0, p): deg, cursor, gsum
    float* dinv      = (float*)(ws + alloc((size_t)NN * 4));
    int*   row_start = (int*)(ws + alloc((size_t)NN * 4));
    int*   partials  = (int*)(ws + alloc(512 * 4));
    int*   csr       = (int*)(ws + alloc((size_t)NE * 4));
    float* rb        = (float*)(ws + alloc(512));
    __hip_bfloat16* bufH = (__hip_bfloat16*)(ws + alloc((size_t)NN * 128 * 2));  // bf16 gather buffer
    float* bufB      = (float*)(ws + alloc((size_t)NN * 128 * 4));               // fp32 agg output
    if (p > ws_size) return;  // workspace too small: fail loudly (validation mismatch)

    const int SB = (NN + 255) / 256;    // scan blocks (391 <= 512)
    const int EB = (NE + 255) / 256;

    hipMemsetAsync(d_ws, 0, zero_bytes, stream);
    count_deg_kernel<<<EB, 256, 0, stream>>>(dst, deg, NE);
    scan_blocks_kernel<<<SB, 256, 0, stream>>>(deg, row_start, partials, NN);
    scan_partials_kernel<<<1, 512, 0, stream>>>(partials, SB);
    scan_add_kernel<<<SB, 256, 0, stream>>>(row_start, partials, NN);
    dinv_kernel<<<(NN + 255) / 256, 256, 0, stream>>>(deg, dinv, NN);
    fill_csr_kernel<<<EB, 256, 0, stream>>>(src, dst, row_start, cursor, csr, NE);
    rvec_kernel<<<1, 128, 0, stream>>>(rates, eW1, eb1, eW2, eb2, conv2W, rb);

    const int GB = (NN + 63) / 64;      // gemm blocks (1563)

    // conv1: h = relu(agg_scaled(bf16(graph@W1 * dinv)) + b1)
    gemm128_kernel<<<GB, 256, 0, stream>>>(graph, conv1W, nullptr, dinv, bufH, NN);
    agg_kernel<true, true, false><<<4096, 128, 0, stream>>>(bufH, bufB, dinv, row_start, csr, conv1b, nullptr, NN, NE);
    // conv2: x = [h, r]; x@W2 = h@W2_top + rb  (rb folded pre-scale)
    gemm128_kernel<<<GB, 256, 0, stream>>>(bufB, conv2W, rb, dinv, bufH, NN);
    agg_kernel<false, true, false><<<4096, 128, 0, stream>>>(bufH, bufB, dinv, row_start, csr, conv2b, nullptr, NN, NE);
    // conv3 (+ fused mean pool)
    gemm128_kernel<<<GB, 256, 0, stream>>>(bufB, conv3W, nullptr, dinv, bufH, NN);
    agg_kernel<false, false, true><<<4096, 128, 0, stream>>>(bufH, nullptr, dinv, row_start, csr, conv3b, gsum, NN, NE);
    // pooled MLP head
    mlp_kernel<<<1, 256, 0, stream>>>(gsum, hidW, hidb, hid2W, hid2b, finW, finb, (float*)d_out, 1.0f / (float)NN);
}